// Round 8
// baseline (10089.427 us; speedup 1.0000x reference)
//
#include <hip/hip_runtime.h>
#include <hip/hip_bf16.h>
#include <stdint.h>

// ---------------------------------------------------------------------------
// 2-layer LSTM (B=256, T=1024, H=256). R16: XCD-LOCAL FAST EXCHANGE.
//
// R15 counters: FETCH_SIZE 2.3GB / 904 GB/s HBM on a 3MB workspace ->
// sc0 sc1 (agent-coherent) polls are served at DRAM-ish latency. All
// R8-R15 protocols paid 3-4 such RTs/step. R16 changes the SCOPE:
//  - Block swizzle co-locates each cluster's 16 WGs on one XCD (assuming
//    round-robin xcd = blockIdx%8; perf-only assumption).
//  - Producers DUAL-PUBLISH h/op/flags: FAST copy (plain store -> local L2)
//    + COHERENT copy (sc0 sc1, R15-proven). Consumers validate per-8B
//    step tags: a tag match is self-certifying no matter which fabric
//    delivered it; miss -> R15 coherent poll. Correctness is placement-
//    independent by construction.
//  - Per-WG learned mode: warmup steps 1..4 probe the fast buffer after
//    each coherent poll success; 4/4 -> fast mode (sc0-only polls, ~300cy
//    L2 RT). Mid-run starvation (4096 tries) reverts to coherent forever.
//  - Everything else (tags, guards, octave reduce, tail, W-permute pack,
//    xpose4, MFMA path) is R15 verbatim (passed).
// ---------------------------------------------------------------------------

#define TT 1024
#define NC 16

typedef __attribute__((ext_vector_type(8))) short  bfrag;
typedef __attribute__((ext_vector_type(4))) float  ffrag;
typedef __attribute__((ext_vector_type(4))) int    ifrag;

__device__ __forceinline__ float sigf(float v){ return 1.f/(1.f+__expf(-v)); }
__device__ __forceinline__ float tanhfast(float v){
    v = fminf(fmaxf(v,-15.f),15.f);
    float e = __expf(2.f*v);
    return (e-1.f)/(e+1.f);
}
__device__ __forceinline__ void st32(uint32_t* p, uint32_t v){
    __hip_atomic_store(p, v, __ATOMIC_RELAXED, __HIP_MEMORY_SCOPE_AGENT);
}
__device__ __forceinline__ void st64(unsigned long long* p, unsigned long long v){
    __hip_atomic_store(p, v, __ATOMIC_RELAXED, __HIP_MEMORY_SCOPE_AGENT);
}
__device__ __forceinline__ void st32_plain(uint32_t* p, uint32_t v){
    __asm__ volatile("global_store_dword %0, %1, off" :: "v"(p), "v"(v) : "memory");
}
__device__ __forceinline__ void st64_plain(unsigned long long* p, unsigned long long v){
    __asm__ volatile("global_store_dwordx2 %0, %1, off" :: "v"(p), "v"(v) : "memory");
}
__device__ __forceinline__ void drain_vmem(){
    __asm__ volatile("s_waitcnt vmcnt(0)" ::: "memory");
}
__device__ __forceinline__ void barrier_raw(){
    __asm__ volatile("s_barrier" ::: "memory");
}
// 4x4 transpose across (reg index) x (lane bits 0-1) - R11..R15-proven.
__device__ __forceinline__ void xpose4(ffrag& a, int lane){
    float x0 = (lane&1) ? a[0] : a[1];
    float y0 = __shfl_xor(x0, 1);
    a[0] = (lane&1) ? y0 : a[0];  a[1] = (lane&1) ? a[1] : y0;
    float x1 = (lane&1) ? a[2] : a[3];
    float y1 = __shfl_xor(x1, 1);
    a[2] = (lane&1) ? y1 : a[2];  a[3] = (lane&1) ? a[3] : y1;
    float x2 = (lane&2) ? a[0] : a[2];
    float y2 = __shfl_xor(x2, 2);
    a[0] = (lane&2) ? y2 : a[0];  a[2] = (lane&2) ? a[2] : y2;
    float x3 = (lane&2) ? a[1] : a[3];
    float y3 = __shfl_xor(x3, 2);
    a[1] = (lane&2) ? y3 : a[1];  a[3] = (lane&2) ? a[3] : y3;
}

__global__ void __launch_bounds__(256, 1)
lstm_kernel(const float* __restrict__ x,
            const float* __restrict__ Wih0, const float* __restrict__ Whh0,
            const float* __restrict__ bih0, const float* __restrict__ bhh0,
            const float* __restrict__ Wih1, const float* __restrict__ Whh1,
            const float* __restrict__ bih1, const float* __restrict__ bhh1,
            const float* __restrict__ Wlin, const float* __restrict__ blin,
            float* __restrict__ out, char* __restrict__ ws)
{
    const int tid = threadIdx.x;
    const int wg  = blockIdx.x;
    // XCD co-location swizzle (bijective): cluster c on XCD c>>1 (2/XCD).
    const int slot_ = wg >> 3;
    const int c   = (wg & 7) * 2 + (slot_ >> 4);
    const int j   = slot_ & 15;
    const bool isL0 = (j < 8);
    const int  u0   = (isL0 ? j : (j - 8)) * 32;

    // ws: flagsC 64KB | flagsF 64KB | h0C 1MB | h1C 1MB | opC 1MB |
    //     h0F 1MB | h1F 1MB | opF 1MB   (~6.1MB total)
    char* flagC = ws + (size_t)c * 4096;
    char* flagF = ws + 65536 + (size_t)c * 4096;
    char* h0tC  = ws + 131072;
    char* h1tC  = h0tC + (size_t)4 * NC * 8 * 2048;
    unsigned long long* opC = (unsigned long long*)(h1tC + (size_t)4 * NC * 8 * 2048);
    char* h0tF  = (char*)opC + (size_t)16 * NC * 16 * 32 * 8;
    char* h1tF  = h0tF + (size_t)4 * NC * 8 * 2048;
    unsigned long long* opF = (unsigned long long*)(h1tF + (size_t)4 * NC * 8 * 2048);

    // LDS: Wt 64KB | Wt2/xs 64KB (aliased) | hs0 8KB | hs1 8KB
    __shared__ __attribute__((aligned(16))) char S[147456];
    __hip_bfloat16* Wt  = (__hip_bfloat16*)S;
    __hip_bfloat16* Wt2 = (__hip_bfloat16*)(S + 65536);
    float*          xs  = (float*)(S + 65536);
    char*           hs0 = S + 131072;
    char*           hs1 = S + 139264;

    const int lane = tid & 63, wave = tid >> 6;
    const int q_l  = (lane >> 2) & 3;
    const int g_l  = lane & 3;
    const int rg   = lane >> 4;
    const int row  = rg * 4 + g_l;
    const int u_e  = wave * 8 + q_l * 2;

    // ---- one-time init (R11+-proven W permutation pack) ----
    {
        const float* Wsrc = isL0 ? Whh0 : Wih1;
        for (int i = tid; i < 128 * 256; i += 256) {
            int n = i >> 8, k = i & 255;
            int ntile = n >> 4, cc = n & 15, q = cc >> 2, g = cc & 3;
            int unit = 8 * (ntile >> 1) + 2 * q + (ntile & 1);
            int r = g * 256 + u0 + unit;
            int ln = (n & 15) | (((k >> 3) & 3) << 4);
            int toff = (ntile * 8 + (k >> 5)) * 1024 + ln * 16 + (k & 7) * 2;
            *(__hip_bfloat16*)((char*)Wt + toff) = __float2bfloat16(Wsrc[r * 256 + k]);
            if (!isL0)
                *(__hip_bfloat16*)((char*)Wt2 + toff) = __float2bfloat16(Whh1[r * 256 + k]);
        }
        if (isL0) {
            for (int i = tid; i < 16 * 1024; i += 256)
                xs[i] = x[(c * 16 + (i & 15)) * TT + (i >> 4)];
        }
        // zero own slot-3 tagged block in BOTH copies (data 0, tag 0)
        size_t zoff = (size_t)((3 * NC + c) * 8 + (isL0 ? j : (j - 8))) * 2048;
        char* zC = (isL0 ? h0tC : h1tC) + zoff;
        char* zF = (isL0 ? h0tF : h1tF) + zoff;
        st64((unsigned long long*)zC + tid, 0ull);
        st64_plain((unsigned long long*)zF + tid, 0ull);
    }
    float be0,be1,be2,be3, bo0,bo1,bo2,bo3;
    float we0=0,we1=0,we2=0,we3=0, wo0=0,wo1=0,wo2=0,wo3=0;
    float wle=0, wlo=0;
    {
        const float* bi = isL0 ? bih0 : bih1;
        const float* bh = isL0 ? bhh0 : bhh1;
        int r0 = u0 + u_e;
        be0 = bi[r0] + bh[r0];               bo0 = bi[r0+1] + bh[r0+1];
        be1 = bi[256+r0] + bh[256+r0];       bo1 = bi[256+r0+1] + bh[256+r0+1];
        be2 = bi[512+r0] + bh[512+r0];       bo2 = bi[512+r0+1] + bh[512+r0+1];
        be3 = bi[768+r0] + bh[768+r0];       bo3 = bi[768+r0+1] + bh[768+r0+1];
        if (isL0) {
            we0 = Wih0[r0];     wo0 = Wih0[r0+1];
            we1 = Wih0[256+r0]; wo1 = Wih0[256+r0+1];
            we2 = Wih0[512+r0]; wo2 = Wih0[512+r0+1];
            we3 = Wih0[768+r0]; wo3 = Wih0[768+r0+1];
        } else {
            wle = Wlin[u0 + u_e]; wlo = Wlin[u0 + u_e + 1];
        }
    }
    const float blin_r = blin[0];
    drain_vmem();
    __syncthreads();
    if (tid == 0) {
        st32((uint32_t*)(flagC + j * 128), 0u);
        st32_plain((uint32_t*)(flagF + j * 128), 0u);
    }

    int* fbC = (int*)flagC; int* fbF = (int*)flagF;
    const int* cL0a = fbC + (wave)      * 32;
    const int* cL0b = fbC + (wave + 4)  * 32;
    const int* cL1a = fbC + (8 + wave)  * 32;
    const int* cL1b = fbC + (12 + wave) * 32;
    const int* gL0a = fbF + (wave)      * 32;
    const int* gL0b = fbF + (wave + 4)  * 32;
    const int* gL1a = fbF + (8 + wave)  * 32;
    const int* gL1b = fbF + (12 + wave) * 32;
    uint32_t* myflagC = (uint32_t*)(fbC + j * 32);
    uint32_t* myflagF = (uint32_t*)(fbF + j * 32);

    const char* wb0 = (const char*)Wt + (wave * 2) * 8192 + lane * 16;
    const char* wb1 = wb0 + 8192;
    const char* wc0 = (const char*)Wt2 + (wave * 2) * 8192 + lane * 16;
    const char* wc1 = wc0 + 8192;
    const int lnt = (lane & 15) * 128 + (lane >> 4) * 32;

    float c0a = 0.f, c0b = 0.f;
    int fastok = 0; bool fastmode = false;

    if (isL0) {
        for (int t = 0; t < TT; ++t) {
            const size_t boff = (size_t)((((t + 3) & 3) * NC + c) * 8) * 2048;
            ifrag r0, r1, r2, r3; int f0, f1, f2, f3;
            bool got = false;
            if (fastmode) {
                const char* pA = h0tF + boff + wave * 2048 + lnt;
                const char* pB = pA + 8192;
                int tries = 0;
                for (;;) {
                    __asm__ volatile(
                        "global_load_dwordx4 %0, %8, off sc0\n\t"
                        "global_load_dwordx4 %1, %8, off offset:16 sc0\n\t"
                        "global_load_dwordx4 %2, %9, off sc0\n\t"
                        "global_load_dwordx4 %3, %9, off offset:16 sc0\n\t"
                        "global_load_dword %4, %10, off sc0\n\t"
                        "global_load_dword %5, %11, off sc0\n\t"
                        "global_load_dword %6, %12, off sc0\n\t"
                        "global_load_dword %7, %13, off sc0\n\t"
                        "s_waitcnt vmcnt(0)"
                        : "=&v"(r0), "=&v"(r1), "=&v"(r2), "=&v"(r3),
                          "=&v"(f0), "=&v"(f1), "=&v"(f2), "=&v"(f3)
                        : "v"(pA), "v"(pB), "v"(gL0a), "v"(gL0b), "v"(gL1a), "v"(gL1b)
                        : "memory");
                    bool ok = (r0.y==t)&(r0.w==t)&(r1.y==t)&(r1.w==t)
                            & (r2.y==t)&(r2.w==t)&(r3.y==t)&(r3.w==t)
                            & (f0>=t-2)&(f1>=t-2)&(f2>=t-3)&(f3>=t-3);
                    if (__all(ok)) { got = true; break; }
                    if (++tries > 4096) { fastmode = false; break; }
                    __builtin_amdgcn_s_sleep(1);
                }
            }
            if (!got) {
                const char* pA = h0tC + boff + wave * 2048 + lnt;
                const char* pB = pA + 8192;
                int bail = 0;
                for (;;) {
                    __asm__ volatile(
                        "global_load_dwordx4 %0, %8, off sc0 sc1\n\t"
                        "global_load_dwordx4 %1, %8, off offset:16 sc0 sc1\n\t"
                        "global_load_dwordx4 %2, %9, off sc0 sc1\n\t"
                        "global_load_dwordx4 %3, %9, off offset:16 sc0 sc1\n\t"
                        "global_load_dword %4, %10, off sc0 sc1\n\t"
                        "global_load_dword %5, %11, off sc0 sc1\n\t"
                        "global_load_dword %6, %12, off sc0 sc1\n\t"
                        "global_load_dword %7, %13, off sc0 sc1\n\t"
                        "s_waitcnt vmcnt(0)"
                        : "=&v"(r0), "=&v"(r1), "=&v"(r2), "=&v"(r3),
                          "=&v"(f0), "=&v"(f1), "=&v"(f2), "=&v"(f3)
                        : "v"(pA), "v"(pB), "v"(cL0a), "v"(cL0b), "v"(cL1a), "v"(cL1b)
                        : "memory");
                    bool ok = (r0.y==t)&(r0.w==t)&(r1.y==t)&(r1.w==t)
                            & (r2.y==t)&(r2.w==t)&(r3.y==t)&(r3.w==t)
                            & (f0>=t-2)&(f1>=t-2)&(f2>=t-3)&(f3>=t-3);
                    if (__all(ok)) break;
                    if (++bail > (1 << 21)) break;
                    if (bail > 1) __builtin_amdgcn_s_sleep(1);
                }
                if (t >= 1 && t <= 4) {            // warmup probe of fast copy
                    const char* qA = h0tF + boff + wave * 2048 + lnt;
                    const char* qB = qA + 8192;
                    ifrag q0, q1, q2, q3; int g0, g1, g2, g3;
                    __asm__ volatile(
                        "global_load_dwordx4 %0, %8, off sc0\n\t"
                        "global_load_dwordx4 %1, %8, off offset:16 sc0\n\t"
                        "global_load_dwordx4 %2, %9, off sc0\n\t"
                        "global_load_dwordx4 %3, %9, off offset:16 sc0\n\t"
                        "global_load_dword %4, %10, off sc0\n\t"
                        "global_load_dword %5, %11, off sc0\n\t"
                        "global_load_dword %6, %12, off sc0\n\t"
                        "global_load_dword %7, %13, off sc0\n\t"
                        "s_waitcnt vmcnt(0)"
                        : "=&v"(q0), "=&v"(q1), "=&v"(q2), "=&v"(q3),
                          "=&v"(g0), "=&v"(g1), "=&v"(g2), "=&v"(g3)
                        : "v"(qA), "v"(qB), "v"(gL0a), "v"(gL0b), "v"(gL1a), "v"(gL1b)
                        : "memory");
                    bool pok = (q0.y==t)&(q0.w==t)&(q1.y==t)&(q1.w==t)
                             & (q2.y==t)&(q2.w==t)&(q3.y==t)&(q3.w==t)
                             & (g0>=t-2)&(g1>=t-2)&(g2>=t-3)&(g3>=t-3);
                    fastok += __all(pok) ? 1 : 0;
                    if (t == 4 && fastok == 4) fastmode = true;
                }
            }
            *(ifrag*)(hs0 + wave * 1024 + lane * 16)       = (ifrag){r0.x, r0.z, r1.x, r1.z};
            *(ifrag*)(hs0 + (wave + 4) * 1024 + lane * 16) = (ifrag){r2.x, r2.z, r3.x, r3.z};
            __asm__ volatile("s_waitcnt lgkmcnt(0)" ::: "memory");
            barrier_raw();
            if (tid == 0) { st32(myflagC, (uint32_t)(t + 1));
                            st32_plain(myflagF, (uint32_t)(t + 1)); }

            const bool red = (t >= 12) && ((t & 7) == 4);
            ifrag o0, o1, o2, o3;
            int rrow = 0, col = 0; const char* ob = nullptr; bool rf = false;
            if (red) {
                rrow = 2 * j + (lane >> 5);
                col  = (t - 12) + ((lane >> 2) & 7);
                int slot = col & 15, p0 = (lane & 3) * 8;
                rf = fastmode;
                ob = (const char*)((rf ? opF : opC)
                     + (size_t)((slot * NC + c) * 16 + rrow) * 32 + p0);
                if (rf) {
                    __asm__ volatile(
                        "global_load_dwordx4 %0, %4, off sc0\n\t"
                        "global_load_dwordx4 %1, %4, off offset:16 sc0\n\t"
                        "global_load_dwordx4 %2, %4, off offset:32 sc0\n\t"
                        "global_load_dwordx4 %3, %4, off offset:48 sc0"
                        : "=&v"(o0), "=&v"(o1), "=&v"(o2), "=&v"(o3)
                        : "v"(ob) : "memory");
                } else {
                    __asm__ volatile(
                        "global_load_dwordx4 %0, %4, off sc0 sc1\n\t"
                        "global_load_dwordx4 %1, %4, off offset:16 sc0 sc1\n\t"
                        "global_load_dwordx4 %2, %4, off offset:32 sc0 sc1\n\t"
                        "global_load_dwordx4 %3, %4, off offset:48 sc0 sc1"
                        : "=&v"(o0), "=&v"(o1), "=&v"(o2), "=&v"(o3)
                        : "v"(ob) : "memory");
                }
            }

            ffrag a0 = {0.f,0.f,0.f,0.f}, a1 = {0.f,0.f,0.f,0.f};
            #pragma unroll
            for (int kt = 0; kt < 8; ++kt) {
                bfrag av = *(const bfrag*)(hs0 + kt * 1024 + lane * 16);
                bfrag b0 = *(const bfrag*)(wb0 + kt * 1024);
                bfrag b1 = *(const bfrag*)(wb1 + kt * 1024);
                a0 = __builtin_amdgcn_mfma_f32_16x16x32_bf16(av, b0, a0, 0, 0, 0);
                a1 = __builtin_amdgcn_mfma_f32_16x16x32_bf16(av, b1, a1, 0, 0, 0);
            }
            xpose4(a0, lane);
            xpose4(a1, lane);

            float xv = xs[t * 16 + row];
            float iv = a0[0] + fmaf(xv, we0, be0);
            float fv = a0[1] + fmaf(xv, we1, be1);
            float gv = a0[2] + fmaf(xv, we2, be2);
            float ov = a0[3] + fmaf(xv, we3, be3);
            c0a = sigf(fv) * c0a + sigf(iv) * tanhfast(gv);
            float hn0 = sigf(ov) * tanhfast(c0a);
            iv = a1[0] + fmaf(xv, wo0, bo0);
            fv = a1[1] + fmaf(xv, wo1, bo1);
            gv = a1[2] + fmaf(xv, wo2, bo2);
            ov = a1[3] + fmaf(xv, wo3, bo3);
            c0b = sigf(fv) * c0b + sigf(iv) * tanhfast(gv);
            float hn1 = sigf(ov) * tanhfast(c0b);

            __hip_bfloat16 hb0 = __float2bfloat16(hn0), hb1 = __float2bfloat16(hn1);
            uint32_t pk = ((uint32_t)(*(uint16_t*)&hb1) << 16) | (uint32_t)(*(uint16_t*)&hb0);
            unsigned long long hv = (unsigned long long)pk
                                  | ((unsigned long long)(uint32_t)(t + 1) << 32);
            size_t poff = (size_t)(((t & 3) * NC + c) * 8 + j) * 2048
                        + row * 128 + (wave * 4 + q_l) * 8;
            st64((unsigned long long*)(h0tC + poff), hv);       // coherent copy
            st64_plain((unsigned long long*)(h0tF + poff), hv); // fast copy

            if (red) {
                // bind op loads; the 2 h-stores stay in flight
                __asm__ volatile("s_waitcnt vmcnt(2)"
                                 : "+v"(o0), "+v"(o1), "+v"(o2), "+v"(o3) :: "memory");
                __builtin_amdgcn_sched_barrier(0);
                int tgt = col + 1, bail2 = 0;
                while (!__all((o0.y==tgt)&(o0.w==tgt)&(o1.y==tgt)&(o1.w==tgt)
                            & (o2.y==tgt)&(o2.w==tgt)&(o3.y==tgt)&(o3.w==tgt))) {
                    if (++bail2 > (1 << 21)) break;
                    if (bail2 == 64 && rf) {    // fast op starved -> coherent
                        rf = false;
                        int slot = col & 15, p0 = (lane & 3) * 8;
                        ob = (const char*)(opC + (size_t)((slot * NC + c) * 16 + rrow) * 32 + p0);
                    }
                    __builtin_amdgcn_s_sleep(1);
                    if (rf) {
                        __asm__ volatile(
                            "global_load_dwordx4 %0, %4, off sc0\n\t"
                            "global_load_dwordx4 %1, %4, off offset:16 sc0\n\t"
                            "global_load_dwordx4 %2, %4, off offset:32 sc0\n\t"
                            "global_load_dwordx4 %3, %4, off offset:48 sc0\n\t"
                            "s_waitcnt vmcnt(0)"
                            : "=&v"(o0), "=&v"(o1), "=&v"(o2), "=&v"(o3)
                            : "v"(ob) : "memory");
                    } else {
                        __asm__ volatile(
                            "global_load_dwordx4 %0, %4, off sc0 sc1\n\t"
                            "global_load_dwordx4 %1, %4, off offset:16 sc0 sc1\n\t"
                            "global_load_dwordx4 %2, %4, off offset:32 sc0 sc1\n\t"
                            "global_load_dwordx4 %3, %4, off offset:48 sc0 sc1\n\t"
                            "s_waitcnt vmcnt(0)"
                            : "=&v"(o0), "=&v"(o1), "=&v"(o2), "=&v"(o3)
                            : "v"(ob) : "memory");
                    }
                }
                float v = __int_as_float(o0.x) + __int_as_float(o0.z)
                        + __int_as_float(o1.x) + __int_as_float(o1.z)
                        + __int_as_float(o2.x) + __int_as_float(o2.z)
                        + __int_as_float(o3.x) + __int_as_float(o3.z);
                v += __shfl_xor(v, 1);
                v += __shfl_xor(v, 2);
                if ((lane & 3) == 0) out[(c * 16 + rrow) * TT + col] = v + blin_r;
            }
            barrier_raw();
        }
        // ---- tail: cols TT-8..TT-1, all L0 WGs (rows 2j,2j+1); coherent ----
        {
            int f2, f3, bail = 0;
            for (;;) {
                __asm__ volatile(
                    "global_load_dword %0, %2, off sc0 sc1\n\t"
                    "global_load_dword %1, %3, off sc0 sc1\n\t"
                    "s_waitcnt vmcnt(0)"
                    : "=&v"(f2), "=&v"(f3) : "v"(cL1a), "v"(cL1b) : "memory");
                if (__all((f2 >= TT + 1) && (f3 >= TT + 1))) break;
                if (++bail > (1 << 22)) break;
                __builtin_amdgcn_s_sleep(1);
            }
            barrier_raw();
            int rrow = 2 * j + (lane >> 5);
            int col  = (TT - 8) + ((lane >> 2) & 7);
            int slot = col & 15, p0 = (lane & 3) * 8;
            const char* ob = (const char*)(opC + (size_t)((slot * NC + c) * 16 + rrow) * 32 + p0);
            ifrag o0, o1, o2, o3; int tgt = col + 1, bail2 = 0;
            for (;;) {
                __asm__ volatile(
                    "global_load_dwordx4 %0, %4, off sc0 sc1\n\t"
                    "global_load_dwordx4 %1, %4, off offset:16 sc0 sc1\n\t"
                    "global_load_dwordx4 %2, %4, off offset:32 sc0 sc1\n\t"
                    "global_load_dwordx4 %3, %4, off offset:48 sc0 sc1\n\t"
                    "s_waitcnt vmcnt(0)"
                    : "=&v"(o0), "=&v"(o1), "=&v"(o2), "=&v"(o3)
                    : "v"(ob) : "memory");
                if (__all((o0.y==tgt)&(o0.w==tgt)&(o1.y==tgt)&(o1.w==tgt)
                        & (o2.y==tgt)&(o2.w==tgt)&(o3.y==tgt)&(o3.w==tgt))) break;
                if (++bail2 > (1 << 21)) break;
                __builtin_amdgcn_s_sleep(1);
            }
            float v = __int_as_float(o0.x) + __int_as_float(o0.z)
                    + __int_as_float(o1.x) + __int_as_float(o1.z)
                    + __int_as_float(o2.x) + __int_as_float(o2.z)
                    + __int_as_float(o3.x) + __int_as_float(o3.z);
            v += __shfl_xor(v, 1);
            v += __shfl_xor(v, 2);
            if ((lane & 3) == 0) out[(c * 16 + rrow) * TT + col] = v + blin_r;
        }
    } else {
        for (int s = 0; s < TT; ++s) {
            const size_t b0off = (size_t)(((s & 3) * NC + c) * 8) * 2048;
            const size_t b1off = (size_t)((((s + 3) & 3) * NC + c) * 8) * 2048;
            ifrag r0, r1, r2, r3, r4, r5, r6, r7; int f0, f1, f2, f3;
            const int e0 = s + 1, e1 = s;
            bool got = false;
            if (fastmode) {
                const char* pA0 = h0tF + b0off + wave * 2048 + lnt;
                const char* pB0 = pA0 + 8192;
                const char* pA1 = h1tF + b1off + wave * 2048 + lnt;
                const char* pB1 = pA1 + 8192;
                int tries = 0;
                for (;;) {
                    __asm__ volatile(
                        "global_load_dwordx4 %0,  %12, off sc0\n\t"
                        "global_load_dwordx4 %1,  %12, off offset:16 sc0\n\t"
                        "global_load_dwordx4 %2,  %13, off sc0\n\t"
                        "global_load_dwordx4 %3,  %13, off offset:16 sc0\n\t"
                        "global_load_dwordx4 %4,  %14, off sc0\n\t"
                        "global_load_dwordx4 %5,  %14, off offset:16 sc0\n\t"
                        "global_load_dwordx4 %6,  %15, off sc0\n\t"
                        "global_load_dwordx4 %7,  %15, off offset:16 sc0\n\t"
                        "global_load_dword %8,  %16, off sc0\n\t"
                        "global_load_dword %9,  %17, off sc0\n\t"
                        "global_load_dword %10, %18, off sc0\n\t"
                        "global_load_dword %11, %19, off sc0\n\t"
                        "s_waitcnt vmcnt(0)"
                        : "=&v"(r0), "=&v"(r1), "=&v"(r2), "=&v"(r3),
                          "=&v"(r4), "=&v"(r5), "=&v"(r6), "=&v"(r7),
                          "=&v"(f0), "=&v"(f1), "=&v"(f2), "=&v"(f3)
                        : "v"(pA0), "v"(pB0), "v"(pA1), "v"(pB1),
                          "v"(gL0a), "v"(gL0b), "v"(gL1a), "v"(gL1b)
                        : "memory");
                    bool ok = (r0.y==e0)&(r0.w==e0)&(r1.y==e0)&(r1.w==e0)
                            & (r2.y==e0)&(r2.w==e0)&(r3.y==e0)&(r3.w==e0)
                            & (r4.y==e1)&(r4.w==e1)&(r5.y==e1)&(r5.w==e1)
                            & (r6.y==e1)&(r6.w==e1)&(r7.y==e1)&(r7.w==e1)
                            & (f0>=s-2)&(f1>=s-2)&(f2>=s-2)&(f3>=s-2);
                    if (__all(ok)) { got = true; break; }
                    if (++tries > 4096) { fastmode = false; break; }
                    __builtin_amdgcn_s_sleep(1);
                }
            }
            if (!got) {
                const char* pA0 = h0tC + b0off + wave * 2048 + lnt;
                const char* pB0 = pA0 + 8192;
                const char* pA1 = h1tC + b1off + wave * 2048 + lnt;
                const char* pB1 = pA1 + 8192;
                int bail = 0;
                for (;;) {
                    __asm__ volatile(
                        "global_load_dwordx4 %0,  %12, off sc0 sc1\n\t"
                        "global_load_dwordx4 %1,  %12, off offset:16 sc0 sc1\n\t"
                        "global_load_dwordx4 %2,  %13, off sc0 sc1\n\t"
                        "global_load_dwordx4 %3,  %13, off offset:16 sc0 sc1\n\t"
                        "global_load_dwordx4 %4,  %14, off sc0 sc1\n\t"
                        "global_load_dwordx4 %5,  %14, off offset:16 sc0 sc1\n\t"
                        "global_load_dwordx4 %6,  %15, off sc0 sc1\n\t"
                        "global_load_dwordx4 %7,  %15, off offset:16 sc0 sc1\n\t"
                        "global_load_dword %8,  %16, off sc0 sc1\n\t"
                        "global_load_dword %9,  %17, off sc0 sc1\n\t"
                        "global_load_dword %10, %18, off sc0 sc1\n\t"
                        "global_load_dword %11, %19, off sc0 sc1\n\t"
                        "s_waitcnt vmcnt(0)"
                        : "=&v"(r0), "=&v"(r1), "=&v"(r2), "=&v"(r3),
                          "=&v"(r4), "=&v"(r5), "=&v"(r6), "=&v"(r7),
                          "=&v"(f0), "=&v"(f1), "=&v"(f2), "=&v"(f3)
                        : "v"(pA0), "v"(pB0), "v"(pA1), "v"(pB1),
                          "v"(cL0a), "v"(cL0b), "v"(cL1a), "v"(cL1b)
                        : "memory");
                    bool ok = (r0.y==e0)&(r0.w==e0)&(r1.y==e0)&(r1.w==e0)
                            & (r2.y==e0)&(r2.w==e0)&(r3.y==e0)&(r3.w==e0)
                            & (r4.y==e1)&(r4.w==e1)&(r5.y==e1)&(r5.w==e1)
                            & (r6.y==e1)&(r6.w==e1)&(r7.y==e1)&(r7.w==e1)
                            & (f0>=s-2)&(f1>=s-2)&(f2>=s-2)&(f3>=s-2);
                    if (__all(ok)) break;
                    if (++bail > (1 << 21)) break;
                    if (bail > 1) __builtin_amdgcn_s_sleep(1);
                }
                if (s >= 1 && s <= 4) {            // warmup probe
                    const char* qA0 = h0tF + b0off + wave * 2048 + lnt;
                    const char* qB0 = qA0 + 8192;
                    const char* qA1 = h1tF + b1off + wave * 2048 + lnt;
                    const char* qB1 = qA1 + 8192;
                    ifrag q0, q1, q2, q3, q4, q5, q6, q7; int g0, g1, g2, g3;
                    __asm__ volatile(
                        "global_load_dwordx4 %0,  %12, off sc0\n\t"
                        "global_load_dwordx4 %1,  %12, off offset:16 sc0\n\t"
                        "global_load_dwordx4 %2,  %13, off sc0\n\t"
                        "global_load_dwordx4 %3,  %13, off offset:16 sc0\n\t"
                        "global_load_dwordx4 %4,  %14, off sc0\n\t"
                        "global_load_dwordx4 %5,  %14, off offset:16 sc0\n\t"
                        "global_load_dwordx4 %6,  %15, off sc0\n\t"
                        "global_load_dwordx4 %7,  %15, off offset:16 sc0\n\t"
                        "global_load_dword %8,  %16, off sc0\n\t"
                        "global_load_dword %9,  %17, off sc0\n\t"
                        "global_load_dword %10, %18, off sc0\n\t"
                        "global_load_dword %11, %19, off sc0\n\t"
                        "s_waitcnt vmcnt(0)"
                        : "=&v"(q0), "=&v"(q1), "=&v"(q2), "=&v"(q3),
                          "=&v"(q4), "=&v"(q5), "=&v"(q6), "=&v"(q7),
                          "=&v"(g0), "=&v"(g1), "=&v"(g2), "=&v"(g3)
                        : "v"(qA0), "v"(qB0), "v"(qA1), "v"(qB1),
                          "v"(gL0a), "v"(gL0b), "v"(gL1a), "v"(gL1b)
                        : "memory");
                    bool pok = (q0.y==e0)&(q0.w==e0)&(q1.y==e0)&(q1.w==e0)
                             & (q2.y==e0)&(q2.w==e0)&(q3.y==e0)&(q3.w==e0)
                             & (q4.y==e1)&(q4.w==e1)&(q5.y==e1)&(q5.w==e1)
                             & (q6.y==e1)&(q6.w==e1)&(q7.y==e1)&(q7.w==e1)
                             & (g0>=s-2)&(g1>=s-2)&(g2>=s-2)&(g3>=s-2);
                    fastok += __all(pok) ? 1 : 0;
                    if (s == 4 && fastok == 4) fastmode = true;
                }
            }
            *(ifrag*)(hs0 + wave * 1024 + lane * 16)       = (ifrag){r0.x, r0.z, r1.x, r1.z};
            *(ifrag*)(hs0 + (wave + 4) * 1024 + lane * 16) = (ifrag){r2.x, r2.z, r3.x, r3.z};
            *(ifrag*)(hs1 + wave * 1024 + lane * 16)       = (ifrag){r4.x, r4.z, r5.x, r5.z};
            *(ifrag*)(hs1 + (wave + 4) * 1024 + lane * 16) = (ifrag){r6.x, r6.z, r7.x, r7.z};
            __asm__ volatile("s_waitcnt lgkmcnt(0)" ::: "memory");
            barrier_raw();
            if (tid == 0) { st32(myflagC, (uint32_t)(s + 1));
                            st32_plain(myflagF, (uint32_t)(s + 1)); }

            ffrag a0 = {0.f,0.f,0.f,0.f}, a1 = {0.f,0.f,0.f,0.f};
            #pragma unroll
            for (int kt = 0; kt < 8; ++kt) {
                bfrag av = *(const bfrag*)(hs0 + kt * 1024 + lane * 16);
                bfrag b0 = *(const bfrag*)(wb0 + kt * 1024);
                bfrag b1 = *(const bfrag*)(wb1 + kt * 1024);
                a0 = __builtin_amdgcn_mfma_f32_16x16x32_bf16(av, b0, a0, 0, 0, 0);
                a1 = __builtin_amdgcn_mfma_f32_16x16x32_bf16(av, b1, a1, 0, 0, 0);
            }
            #pragma unroll
            for (int kt = 0; kt < 8; ++kt) {
                bfrag av = *(const bfrag*)(hs1 + kt * 1024 + lane * 16);
                bfrag b0 = *(const bfrag*)(wc0 + kt * 1024);
                bfrag b1 = *(const bfrag*)(wc1 + kt * 1024);
                a0 = __builtin_amdgcn_mfma_f32_16x16x32_bf16(av, b0, a0, 0, 0, 0);
                a1 = __builtin_amdgcn_mfma_f32_16x16x32_bf16(av, b1, a1, 0, 0, 0);
            }
            xpose4(a0, lane);
            xpose4(a1, lane);

            float iv = a0[0] + be0, fv = a0[1] + be1;
            float gv = a0[2] + be2, ov = a0[3] + be3;
            c0a = sigf(fv) * c0a + sigf(iv) * tanhfast(gv);
            float hn0 = sigf(ov) * tanhfast(c0a);
            iv = a1[0] + bo0; fv = a1[1] + bo1;
            gv = a1[2] + bo2; ov = a1[3] + bo3;
            c0b = sigf(fv) * c0b + sigf(iv) * tanhfast(gv);
            float hn1 = sigf(ov) * tanhfast(c0b);

            __hip_bfloat16 hb0 = __float2bfloat16(hn0), hb1 = __float2bfloat16(hn1);
            uint32_t pk = ((uint32_t)(*(uint16_t*)&hb1) << 16) | (uint32_t)(*(uint16_t*)&hb0);

            float pv = hn0 * wle + hn1 * wlo;
            pv += __shfl_xor(pv, 4);
            pv += __shfl_xor(pv, 8);

            unsigned long long hv = (unsigned long long)pk
                                  | ((unsigned long long)(uint32_t)(s + 1) << 32);
            size_t poff = (size_t)(((s & 3) * NC + c) * 8 + (j - 8)) * 2048
                        + row * 128 + (wave * 4 + q_l) * 8;
            st64((unsigned long long*)(h1tC + poff), hv);
            st64_plain((unsigned long long*)(h1tF + poff), hv);
            if ((lane & 12) == 0) {
                size_t ooff = (size_t)(((s & 15) * NC + c) * 16 + row) * 32 + (j - 8) * 4 + wave;
                unsigned long long ov2 = (unsigned long long)__float_as_uint(pv)
                                       | ((unsigned long long)(uint32_t)(s + 1) << 32);
                st64(opC + ooff, ov2);
                st64_plain(opF + ooff, ov2);
            }
            barrier_raw();
        }
        if (tid == 0) { st32(myflagC, (uint32_t)(TT + 1));
                        st32_plain(myflagF, (uint32_t)(TT + 1)); }
    }
}

extern "C" void kernel_launch(void* const* d_in, const int* in_sizes, int n_in,
                              void* d_out, int out_size, void* d_ws, size_t ws_size,
                              hipStream_t stream)
{
    const float* x    = (const float*)d_in[0];
    const float* Wih0 = (const float*)d_in[1];
    const float* Whh0 = (const float*)d_in[2];
    const float* bih0 = (const float*)d_in[3];
    const float* bhh0 = (const float*)d_in[4];
    const float* Wih1 = (const float*)d_in[5];
    const float* Whh1 = (const float*)d_in[6];
    const float* bih1 = (const float*)d_in[7];
    const float* bhh1 = (const float*)d_in[8];
    const float* Wlin = (const float*)d_in[9];
    const float* blin = (const float*)d_in[10];
    float* out = (float*)d_out;
    char* ws   = (char*)d_ws;

    // 256 blocks x 256 threads, 1 block/CU -> all co-resident (spin-safe).
    lstm_kernel<<<dim3(256), dim3(256), 0, stream>>>(
        x, Wih0, Whh0, bih0, bhh0, Wih1, Whh1, bih1, bhh1, Wlin, blin, out, ws);
}